// Round 1
// 306.578 us; speedup vs baseline: 1.0293x; 1.0293x over previous
//
#include <hip/hip_runtime.h>

typedef _Float16 f16;
typedef __attribute__((ext_vector_type(4))) _Float16 f16x4;
typedef __attribute__((ext_vector_type(8))) _Float16 f16x8;
typedef __attribute__((ext_vector_type(4))) float f32x4;

#define GLB_AS __attribute__((address_space(1)))
#define LDS_AS __attribute__((address_space(3)))

__device__ __forceinline__ void async_copy16(const void* g, void* l) {
  // 16B-per-lane global->LDS DMA; LDS dest = wave-uniform base + lane*16
  __builtin_amdgcn_global_load_lds((const GLB_AS void*)g, (LDS_AS void*)l, 16, 0, 0);
}

// ---------------------------------------------------------------------------
// Generic fp16 GEMM: C[m][n] = sum_k A[m*lda+k] * B[n*ldb+k]   (both K-contig)
// BM=BN=128, BK=32, 256 threads (4 waves, 2x2), each wave 64x64 via 4x4 MFMA.
// Double-buffered LDS: prefetch tile k+1 right after the barrier, compute
// tile k -> ONE barrier per iteration and the vmcnt(0) drain overlaps the
// whole MFMA body instead of being exposed back-to-back with the loads.
//
// LDS chunk swizzle (rule 21: both-sides-or-neither with global_load_lds):
// rows are 64 B = 4 chunks of 16 B. Linear layout gives an 8-way bank
// conflict on the fragment ds_read_b128 (row-stride 16 dwords -> 2 bank
// groups per quad). We XOR the chunk index with g(r) = (r ^ (r>>2)) & 3:
//  - staging permutes the per-lane GLOBAL source chunk (LDS dest stays
//    linear, coalescing unchanged: same 64 B per 4-lane group)
//  - the read applies the same XOR
// Result: each 16-lane phase covers all 32 banks exactly 2x (free, m136).
//
// 1D grid with explicit tile decode for XCD-aware L2 locality (XCD = n%8):
//  MODE 0 (projection): y-inner, (x,z)-outer -> XCD j owns row-slab y==j mod 8
//  MODE 1 (attention, ty=16, tz=4): z = (n%8)>>1 -> batch bound to an XCD pair
// ---------------------------------------------------------------------------
template <typename OutT, int MODE, bool BIAS>
__global__ __launch_bounds__(256) void gemm_kn(
    const f16* __restrict__ A, const f16* __restrict__ B, OutT* __restrict__ C,
    int lda, int ldb, int ldc, int K, long sA, long sB, long sC,
    int tiles_x, int tiles_y,
    const float* __restrict__ b0, const float* __restrict__ b1,
    const float* __restrict__ b2)
{
  constexpr int BM = 128, BK = 32;
  __shared__ __align__(16) f16 Ash[2][BM * BK];
  __shared__ __align__(16) f16 Bsh[2][BM * BK];

  int bx, by, bz;
  {
    const int n = blockIdx.x;
    if (MODE == 0) {
      by = n % tiles_y;
      const int r = n / tiles_y;
      bx = r % tiles_x;
      bz = r / tiles_x;
    } else {
      const int j = n & 7, i = n >> 3;
      bz = j >> 1;                     // batch <- XCD pair
      bx = i >> 3;                     // x-outer: B-tile resident per step
      by = (j & 1) * 8 + (i & 7);      // y-inner within this XCD's half
    }
  }

  A += (long)bz * sA;
  B += (long)bz * sB;
  C += (long)bz * sC;

  const int tid  = threadIdx.x;
  const int wave = tid >> 6, lane = tid & 63;
  const int m0 = by * BM, n0 = bx * BM;
  const int wm = (wave >> 1) * 64, wn = (wave & 1) * 64;
  const int r16 = lane & 15, quad = lane >> 4;

  // staging: each wave fills rows [wave*32, wave*32+32) of both tiles,
  // 2 chunks of 16 rows; lane l -> row +(l>>2); global k-chunk is the
  // SWIZZLED chunk ((l&3) ^ g(l>>2)) * 8 elements (16B) so that the linear
  // LDS write realizes the swizzled layout.
  const int srow_l = lane >> 2;
  const int srow = wave * 32 + srow_l;
  const int skb  = (((lane & 3) ^ ((srow_l ^ (srow_l >> 2)) & 3)) * 8);
  const f16* Ag = A + (long)(m0 + srow) * lda + skb;
  const f16* Bg = B + (long)(n0 + srow) * ldb + skb;
  const int lo0 = (wave * 32) * BK;        // LDS row offset, 16-row chunk 0
  const int lo1 = (wave * 32 + 16) * BK;   // chunk 1

  // prologue: fill buffer 0
  async_copy16(Ag,                  &Ash[0][lo0]);
  async_copy16(Ag + 16 * (long)lda, &Ash[0][lo1]);
  async_copy16(Bg,                  &Bsh[0][lo0]);
  async_copy16(Bg + 16 * (long)ldb, &Bsh[0][lo1]);

  f32x4 acc[4][4] = {};

  // fragment-read chunk: same XOR as staging, invariant per lane
  const int cchunk = (quad ^ ((r16 ^ (r16 >> 2)) & 3)) * 8;

  int buf = 0;
  for (int k0 = 0; k0 < K; k0 += BK, buf ^= 1) {
    __syncthreads();  // vmcnt(0): prefetch landed; all waves done with buf^1

    if (k0 + BK < K) {
      const int nb = buf ^ 1;
      const long k1 = k0 + BK;
      async_copy16(Ag + k1,                  &Ash[nb][lo0]);
      async_copy16(Ag + k1 + 16 * (long)lda, &Ash[nb][lo1]);
      async_copy16(Bg + k1,                  &Bsh[nb][lo0]);
      async_copy16(Bg + k1 + 16 * (long)ldb, &Bsh[nb][lo1]);
    }

    f16x8 af[4], bf[4];
#pragma unroll
    for (int i = 0; i < 4; i++) {
      af[i] = *(const f16x8*)&Ash[buf][(wm + i * 16 + r16) * BK + cchunk];
      bf[i] = *(const f16x8*)&Bsh[buf][(wn + i * 16 + r16) * BK + cchunk];
    }
#pragma unroll
    for (int i = 0; i < 4; i++)
#pragma unroll
      for (int j = 0; j < 4; j++)
        acc[i][j] = __builtin_amdgcn_mfma_f32_16x16x32_f16(af[i], bf[j], acc[i][j], 0, 0, 0);
  }

  // C/D layout (verified m89): col = lane&15, row = (lane>>4)*4 + reg
  float bias_j[4] = {0.f, 0.f, 0.f, 0.f};
  if (BIAS) {
    const float* bias = (bz == 0) ? b0 : (bz == 1) ? b1 : b2;
#pragma unroll
    for (int j = 0; j < 4; j++) bias_j[j] = bias[n0 + wn + j * 16 + r16];
  }
#pragma unroll
  for (int i = 0; i < 4; i++)
#pragma unroll
    for (int j = 0; j < 4; j++)
#pragma unroll
      for (int r = 0; r < 4; r++) {
        long row = m0 + wm + i * 16 + quad * 4 + r;
        long col = n0 + wn + j * 16 + r16;
        C[row * (long)ldc + col] = (OutT)(acc[i][j][r] + bias_j[j]);
      }
}

// ---------------------------------------------------------------------------
// One launch casts x (8.39M) + Wq/Wk/Wv (1.05M each) fp32 -> fp16.
__global__ __launch_bounds__(256) void cast_all(
    const float* __restrict__ x, const float* __restrict__ Wq,
    const float* __restrict__ Wk, const float* __restrict__ Wv,
    f16* __restrict__ Xh, f16* __restrict__ Wh)
{
  const long off = (long)blockIdx.x * 1024 + threadIdx.x * 4;
  const float* src;
  f16* dst;
  if (off < 8388608L) {
    src = x + off;
    dst = Xh + off;
  } else {
    const long o = off - 8388608L;
    src = (o < 1048576L) ? Wq + o
        : (o < 2097152L) ? Wk + (o - 1048576L)
                         : Wv + (o - 2097152L);
    dst = Wh + o;
  }
  const float4 v = *(const float4*)src;
  f16x4 h;
  h.x = (f16)v.x; h.y = (f16)v.y; h.z = (f16)v.z; h.w = (f16)v.w;
  *(f16x4*)dst = h;
}

// LayerNorm (gamma/beta; bias already folded into GEMM epilogue).
// One block per row, in-place fp16. grid (8192, 3)
__global__ __launch_bounds__(256) void ln_kernel(
    f16* __restrict__ P, const float* __restrict__ gamma,
    const float* __restrict__ beta)
{
  f16* p = P + (long)blockIdx.y * 8388608 + (long)blockIdx.x * 1024;
  const int tid = threadIdx.x;
  const int e = tid * 4;

  f16x4 raw = *(const f16x4*)(p + e);
  float v0 = (float)raw.x, v1 = (float)raw.y;
  float v2 = (float)raw.z, v3 = (float)raw.w;
  float s  = v0 + v1 + v2 + v3;
  float s2 = v0 * v0 + v1 * v1 + v2 * v2 + v3 * v3;

#pragma unroll
  for (int off = 32; off > 0; off >>= 1) {
    s  += __shfl_down(s, off, 64);
    s2 += __shfl_down(s2, off, 64);
  }
  __shared__ float red[10];
  const int wave = tid >> 6, lane = tid & 63;
  if (lane == 0) { red[wave] = s; red[4 + wave] = s2; }
  __syncthreads();
  if (tid == 0) {
    red[8] = red[0] + red[1] + red[2] + red[3];
    red[9] = red[4] + red[5] + red[6] + red[7];
  }
  __syncthreads();
  const float mu   = red[8] * (1.f / 1024.f);
  const float var  = red[9] * (1.f / 1024.f) - mu * mu;
  const float rstd = rsqrtf(var + 1e-5f);

  float4 gg = *(const float4*)(gamma + e);
  float4 be = *(const float4*)(beta + e);
  f16x4 o;
  o.x = (f16)((v0 - mu) * rstd * gg.x + be.x);
  o.y = (f16)((v1 - mu) * rstd * gg.y + be.y);
  o.z = (f16)((v2 - mu) * rstd * gg.z + be.z);
  o.w = (f16)((v3 - mu) * rstd * gg.w + be.w);
  *(f16x4*)(p + e) = o;
}

// V (S x D, fp16) -> Vt (D x S, fp16), per batch. grid (D/64, S/64, B)
__global__ __launch_bounds__(256) void transpose_kernel(const f16* __restrict__ V,
                                                        f16* __restrict__ Vt)
{
  const int S = 2048, D = 1024;
  const f16* v = V + (long)blockIdx.z * ((long)S * D);
  f16* vt = Vt + (long)blockIdx.z * ((long)D * S);
  __shared__ f16 tile[64][66];  // +2 pad -> conflict-free transposed reads
  const int d0 = blockIdx.x * 64, j0 = blockIdx.y * 64;
  const int tx = threadIdx.x & 63, ty = threadIdx.x >> 6;
#pragma unroll
  for (int r = ty; r < 64; r += 4)
    tile[r][tx] = v[(long)(j0 + r) * D + d0 + tx];
  __syncthreads();
#pragma unroll
  for (int r = ty; r < 64; r += 4)
    vt[(long)(d0 + r) * S + j0 + tx] = tile[tx][r];
}

// Row softmax over 2048 fp32 logits; writes fp16 probs in-place (first half of row).
__global__ __launch_bounds__(256) void softmax_kernel(float* __restrict__ Sc)
{
  float* srow = Sc + (long)blockIdx.x * 2048;
  const int tid = threadIdx.x;
  float4 a = ((const float4*)srow)[tid];
  float4 b = ((const float4*)srow)[256 + tid];

  float m = fmaxf(fmaxf(fmaxf(a.x, a.y), fmaxf(a.z, a.w)),
                  fmaxf(fmaxf(b.x, b.y), fmaxf(b.z, b.w)));
#pragma unroll
  for (int off = 32; off > 0; off >>= 1) m = fmaxf(m, __shfl_down(m, off, 64));
  __shared__ float red[6];
  const int wave = tid >> 6, lane = tid & 63;
  if (lane == 0) red[wave] = m;
  __syncthreads();
  if (tid == 0) red[4] = fmaxf(fmaxf(red[0], red[1]), fmaxf(red[2], red[3]));
  __syncthreads();
  const float M = red[4];

  a.x = __expf(a.x - M); a.y = __expf(a.y - M);
  a.z = __expf(a.z - M); a.w = __expf(a.w - M);
  b.x = __expf(b.x - M); b.y = __expf(b.y - M);
  b.z = __expf(b.z - M); b.w = __expf(b.w - M);
  float s = a.x + a.y + a.z + a.w + b.x + b.y + b.z + b.w;
#pragma unroll
  for (int off = 32; off > 0; off >>= 1) s += __shfl_down(s, off, 64);
  if (lane == 0) red[wave] = s;
  __syncthreads();
  if (tid == 0) red[5] = red[0] + red[1] + red[2] + red[3];
  __syncthreads();
  const float inv = 1.0f / red[5];

  f16* orow = (f16*)srow;  // safe: all reads happened before first barrier
  f16x4 oa, ob;
  oa.x = (f16)(a.x * inv); oa.y = (f16)(a.y * inv);
  oa.z = (f16)(a.z * inv); oa.w = (f16)(a.w * inv);
  ob.x = (f16)(b.x * inv); ob.y = (f16)(b.y * inv);
  ob.z = (f16)(b.z * inv); ob.w = (f16)(b.w * inv);
  ((f16x4*)orow)[tid]       = oa;
  ((f16x4*)orow)[256 + tid] = ob;
}

// ---------------------------------------------------------------------------
extern "C" void kernel_launch(void* const* d_in, const int* in_sizes, int n_in,
                              void* d_out, int out_size, void* d_ws, size_t ws_size,
                              hipStream_t stream)
{
  const float* x     = (const float*)d_in[0];
  const float* Wq    = (const float*)d_in[1];
  const float* bq    = (const float*)d_in[2];
  const float* Wk    = (const float*)d_in[3];
  const float* bk    = (const float*)d_in[4];
  const float* Wv    = (const float*)d_in[5];
  const float* bv    = (const float*)d_in[6];
  const float* gamma = (const float*)d_in[7];
  const float* beta  = (const float*)d_in[8];
  float* out = (float*)d_out;

  // ws layout (needs 128 MB):
  //  [0,48)MB   P  : Q,K,V fp16 slabs (8192x1024 each), LN in-place
  //  [48,64)MB  Vt : V transposed per batch (1024x2048 fp16)
  //  [64,128)MB Sc : scores fp32 (4 x 2048x2048); softmax writes fp16 probs in-place
  //  Xh/Wh aliased inside the Sc region (dead before scores are written)
  char* ws = (char*)d_ws;
  f16*   P  = (f16*)(ws);
  f16*   Vt = (f16*)(ws + (48u << 20));
  float* Sc = (float*)(ws + (64u << 20));
  f16*   Xh = (f16*)(ws + (64u << 20));
  f16*   Wh = (f16*)(ws + (80u << 20));

  // 1. fp32 -> fp16 casts (single launch)
  cast_all<<<11264, 256, 0, stream>>>(x, Wq, Wk, Wv, Xh, Wh);

  // 2. projections + bias: P_h = Xh · Wh^T + b_h  (M=8192, N=1024, K=1024, z=h)
  gemm_kn<f16, 0, true><<<1536, 256, 0, stream>>>(
      Xh, Wh, P, 1024, 1024, 1024, 1024, 0L, 1048576L, 8388608L,
      8, 64, bq, bk, bv);

  // 3. LayerNorm (gamma/beta), in-place fp16
  ln_kernel<<<dim3(8192, 3), 256, 0, stream>>>(P, gamma, beta);

  // 4. V -> Vt per batch
  transpose_kernel<<<dim3(16, 32, 4), 256, 0, stream>>>(P + 2L * 8388608, Vt);

  // 5. scores: Sc_b = Q_b · K_b^T  (M=N=2048, K=1024, z=batch, fp32 out)
  gemm_kn<float, 1, false><<<1024, 256, 0, stream>>>(
      P, P + 8388608, Sc, 1024, 1024, 2048, 1024, 2097152L, 2097152L, 4194304L,
      16, 16, nullptr, nullptr, nullptr);

  // 6. softmax rows (8192 rows), fp16 probs in-place (row pitch 4096 halves)
  softmax_kernel<<<8192, 256, 0, stream>>>(Sc);

  // 7. out_b = Pr_b · Vt_b^T  (M=2048, N=1024, K=2048, z=batch, fp32 out)
  gemm_kn<float, 1, false><<<512, 256, 0, stream>>>(
      (const f16*)Sc, Vt, out, 4096, 2048, 1024, 2048, 8388608L, 2097152L, 2097152L,
      8, 16, nullptr, nullptr, nullptr);
}

// Round 2
// 305.048 us; speedup vs baseline: 1.0344x; 1.0050x over previous
//
#include <hip/hip_runtime.h>

typedef _Float16 f16;
typedef __attribute__((ext_vector_type(4))) _Float16 f16x4;
typedef __attribute__((ext_vector_type(8))) _Float16 f16x8;
typedef __attribute__((ext_vector_type(4))) float f32x4;

#define GLB_AS __attribute__((address_space(1)))
#define LDS_AS __attribute__((address_space(3)))

__device__ __forceinline__ void async_copy16(const void* g, void* l) {
  // 16B-per-lane global->LDS DMA; LDS dest = wave-uniform base + lane*16
  __builtin_amdgcn_global_load_lds((const GLB_AS void*)g, (LDS_AS void*)l, 16, 0, 0);
}

#define WAITVM(N) asm volatile("s_waitcnt vmcnt(" #N ")" ::: "memory")
#define WAITLGKM0() asm volatile("s_waitcnt lgkmcnt(0)" ::: "memory")

// Stage macros: per-tile issue order is A-insts then B-insts (vmcnt counting
// relies on per-tile groups being contiguous in issue order).
#define STAGE_A(t_) do {                                                     \
    const int _b = (t_) & 3; const long _k = (long)(t_) * 32;                \
    async_copy16(Ag + _k, &Ash[_b][sl]);                                     \
    if constexpr (IA == 2)                                                   \
      async_copy16(Ag + _k + 128l * lda, &Ash[_b][sl + 128 * 32]);           \
  } while (0)
#define STAGE_B(t_) do {                                                     \
    const int _b = (t_) & 3; const long _k = (long)(t_) * 32;                \
    async_copy16(Bg + _k, &Bsh[_b][sl]);                                     \
    if constexpr (IB == 2)                                                   \
      async_copy16(Bg + _k + 128l * ldb, &Bsh[_b][sl + 128 * 32]);           \
  } while (0)

// ---------------------------------------------------------------------------
// Phase-split GEMM with counted vmcnt (T3+T4+T5): C[m][n] = sum_k A[m][k]*B[n][k]
// 512 threads = 8 waves (2 x 4). BK=32. 4-deep circular LDS buffer: while
// computing tile t, issue staging for tile t+3 (overwrites buf used by t-1,
// already barrier-fenced). Tile boundary waits vmcnt(2*IT) -- tiles t+1, t+2
// stay in flight across the barrier; never vmcnt(0) until the epilogue.
// Per tile: 2 phases, each { ds_read subtile | issue stage -> s_barrier ->
// lgkmcnt(0) -> setprio(1) MFMA cluster setprio(0) -> s_barrier }.
//
// LDS chunk-XOR swizzle (both-sides, rule 21): stage fetches global chunk
// (l&3)^((l>>3)&3) into linear LDS; reads use chunk quad^((r16>>1)&3).
// Guarantees <=2-way banking independent of HW phase grouping.
//
// NOTE on SQ_LDS_BANK_CONFLICT: the counter is dominated by the DMA-write
// artifact (8 cycles per 1024B global_load_lds) = 8 x inst count. Reads are
// conflict-free (verified round 0/1: counter == 8 x stage insts exactly).
//
// MODE 0 (projection): y-inner, (x,z)-outer -> XCD j owns row-slab y==j mod 8
// MODE 1 (attention):  z = (n%8)>>1 -> batch bound to an XCD pair
// ---------------------------------------------------------------------------
template <int BM, int BN, typename OutT, int MODE, bool BIAS>
__global__ __launch_bounds__(512, 2) void gemm8p(
    const f16* __restrict__ A, const f16* __restrict__ B, OutT* __restrict__ C,
    int lda, int ldb, int ldc, int K, long sA, long sB, long sC,
    int tiles_x, int tiles_y,
    const float* __restrict__ b0, const float* __restrict__ b1,
    const float* __restrict__ b2)
{
  constexpr int BK = 32;
  constexpr int WM = BM / 2, WN = BN / 4;     // per-wave output
  constexpr int RM = WM / 16, RN = WN / 16;   // frag repeats: (8,4) or (4,4)
  constexpr int IA = BM / 128, IB = BN / 128; // stage insts per thread
  constexpr int IT = IA + IB;                 // 4 (256x256) or 3 (128x256)

  __shared__ __align__(16) f16 Ash[4][BM * BK];
  __shared__ __align__(16) f16 Bsh[4][BN * BK];

  int bx, by, bz;
  {
    const int n = blockIdx.x;
    if (MODE == 0) {
      by = n % tiles_y;
      const int r = n / tiles_y;
      bx = r % tiles_x;
      bz = r / tiles_x;
    } else {
      const int j = n & 7, i = n >> 3, th = tiles_y >> 1;
      bz = j >> 1;
      bx = i / th;
      by = (j & 1) * th + i % th;
    }
  }

  A += (long)bz * sA;
  B += (long)bz * sB;
  C += (long)bz * sC;

  const int tid  = threadIdx.x;
  const int wave = tid >> 6, lane = tid & 63;
  const int wr = wave >> 2, wc = wave & 3;
  const int m0 = by * BM, n0 = bx * BN;
  const int r16 = lane & 15, quad = lane >> 4;

  // staging: inst q covers rows [ (q*8+wave)*16, +16 ); lane l -> row +(l>>2),
  // global chunk ((l&3)^((l>>3)&3))*8 halves (16B); LDS dest linear.
  const int srow = wave * 16 + (lane >> 2);
  const int schunk = ((lane & 3) ^ ((lane >> 3) & 3)) * 8;
  const f16* Ag = A + (long)(m0 + srow) * lda + schunk;
  const f16* Bg = B + (long)(n0 + srow) * ldb + schunk;
  const int sl = (wave * 16) * BK;  // wave-uniform LDS base (halves)

  const int NT = K / BK;  // >= 32 for all shapes here

  // prologue: stage tiles 0,1,2 (3*IT insts in flight)
  STAGE_A(0); STAGE_B(0);
  STAGE_A(1); STAGE_B(1);
  STAGE_A(2); STAGE_B(2);

  f32x4 acc[RM][RN] = {};

  // fragment-read addresses (chunk-XOR matches staging; bases mult. of 16)
  const int rchunk = (quad ^ ((r16 >> 1) & 3)) * 8;
  const int rdA = (wr * WM + r16) * BK + rchunk;
  const int rdB = (wc * WN + r16) * BK + rchunk;

  for (int t = 0; t < NT; ++t) {
    // tile boundary: tile t must be landed; keep t+1, t+2 in flight
    if constexpr (IT == 4) {
      if (t < NT - 2) { WAITVM(8); } else if (t == NT - 2) { WAITVM(4); } else { WAITVM(0); }
    } else {
      if (t < NT - 2) { WAITVM(6); } else if (t == NT - 2) { WAITVM(3); } else { WAITVM(0); }
    }
    __builtin_amdgcn_s_barrier();

    const f16* As = Ash[t & 3];
    const f16* Bs = Bsh[t & 3];
    f16x8 af[4], bf[RN];

    if constexpr (RM == 8) {
      // ---- phase A: bf[0..3] + af rows 0..3; stage A of t+3; MFMA quad 1
#pragma unroll
      for (int j = 0; j < RN; j++) bf[j] = *(const f16x8*)&Bs[rdB + j * 16 * BK];
#pragma unroll
      for (int i = 0; i < 4; i++) af[i] = *(const f16x8*)&As[rdA + i * 16 * BK];
      if (t + 3 < NT) STAGE_A(t + 3);
      __builtin_amdgcn_s_barrier();
      WAITLGKM0();
      __builtin_amdgcn_sched_barrier(0);
      __builtin_amdgcn_s_setprio(1);
#pragma unroll
      for (int i = 0; i < 4; i++)
#pragma unroll
        for (int j = 0; j < RN; j++)
          acc[i][j] = __builtin_amdgcn_mfma_f32_16x16x32_f16(af[i], bf[j], acc[i][j], 0, 0, 0);
      __builtin_amdgcn_s_setprio(0);
      __builtin_amdgcn_sched_barrier(0);
      __builtin_amdgcn_s_barrier();
      // ---- phase B: af rows 4..7; stage B of t+3; MFMA quad 2
      f16x8 af1[4];
#pragma unroll
      for (int i = 0; i < 4; i++) af1[i] = *(const f16x8*)&As[rdA + (4 + i) * 16 * BK];
      if (t + 3 < NT) STAGE_B(t + 3);
      __builtin_amdgcn_s_barrier();
      WAITLGKM0();
      __builtin_amdgcn_sched_barrier(0);
      __builtin_amdgcn_s_setprio(1);
#pragma unroll
      for (int i = 0; i < 4; i++)
#pragma unroll
        for (int j = 0; j < RN; j++)
          acc[4 + i][j] = __builtin_amdgcn_mfma_f32_16x16x32_f16(af1[i], bf[j], acc[4 + i][j], 0, 0, 0);
      __builtin_amdgcn_s_setprio(0);
      __builtin_amdgcn_sched_barrier(0);
    } else {
      // RM==4: phase A: af all + bf[0..1]; phase B: bf[2..3] (af reused)
#pragma unroll
      for (int i = 0; i < 4; i++) af[i] = *(const f16x8*)&As[rdA + i * 16 * BK];
#pragma unroll
      for (int j = 0; j < 2; j++) bf[j] = *(const f16x8*)&Bs[rdB + j * 16 * BK];
      if (t + 3 < NT) STAGE_A(t + 3);
      __builtin_amdgcn_s_barrier();
      WAITLGKM0();
      __builtin_amdgcn_sched_barrier(0);
      __builtin_amdgcn_s_setprio(1);
#pragma unroll
      for (int i = 0; i < 4; i++)
#pragma unroll
        for (int j = 0; j < 2; j++)
          acc[i][j] = __builtin_amdgcn_mfma_f32_16x16x32_f16(af[i], bf[j], acc[i][j], 0, 0, 0);
      __builtin_amdgcn_s_setprio(0);
      __builtin_amdgcn_sched_barrier(0);
      __builtin_amdgcn_s_barrier();
      // ---- phase B
#pragma unroll
      for (int j = 2; j < 4; j++) bf[j] = *(const f16x8*)&Bs[rdB + j * 16 * BK];
      if (t + 3 < NT) STAGE_B(t + 3);
      __builtin_amdgcn_s_barrier();
      WAITLGKM0();
      __builtin_amdgcn_sched_barrier(0);
      __builtin_amdgcn_s_setprio(1);
#pragma unroll
      for (int i = 0; i < 4; i++)
#pragma unroll
        for (int j = 2; j < 4; j++)
          acc[i][j] = __builtin_amdgcn_mfma_f32_16x16x32_f16(af[i], bf[j], acc[i][j], 0, 0, 0);
      __builtin_amdgcn_s_setprio(0);
      __builtin_amdgcn_sched_barrier(0);
    }
  }

  // epilogue. C/D layout (verified m89): col = lane&15, row = (lane>>4)*4 + reg
  float bias_j[RN];
#pragma unroll
  for (int j = 0; j < RN; j++) bias_j[j] = 0.f;
  if constexpr (BIAS) {
    const float* bias = (bz == 0) ? b0 : (bz == 1) ? b1 : b2;
#pragma unroll
    for (int j = 0; j < RN; j++) bias_j[j] = bias[n0 + wc * WN + j * 16 + r16];
  }
#pragma unroll
  for (int i = 0; i < RM; i++)
#pragma unroll
    for (int j = 0; j < RN; j++)
#pragma unroll
      for (int r = 0; r < 4; r++) {
        long row = m0 + wr * WM + i * 16 + quad * 4 + r;
        long col = n0 + wc * WN + j * 16 + r16;
        C[row * (long)ldc + col] = (OutT)(acc[i][j][r] + bias_j[j]);
      }
}

// ---------------------------------------------------------------------------
// One launch casts x (8.39M) + Wq/Wk/Wv (1.05M each) fp32 -> fp16.
__global__ __launch_bounds__(256) void cast_all(
    const float* __restrict__ x, const float* __restrict__ Wq,
    const float* __restrict__ Wk, const float* __restrict__ Wv,
    f16* __restrict__ Xh, f16* __restrict__ Wh)
{
  const long off = (long)blockIdx.x * 1024 + threadIdx.x * 4;
  const float* src;
  f16* dst;
  if (off < 8388608L) {
    src = x + off;
    dst = Xh + off;
  } else {
    const long o = off - 8388608L;
    src = (o < 1048576L) ? Wq + o
        : (o < 2097152L) ? Wk + (o - 1048576L)
                         : Wv + (o - 2097152L);
    dst = Wh + o;
  }
  const float4 v = *(const float4*)src;
  f16x4 h;
  h.x = (f16)v.x; h.y = (f16)v.y; h.z = (f16)v.z; h.w = (f16)v.w;
  *(f16x4*)dst = h;
}

// LayerNorm (gamma/beta; bias already folded into GEMM epilogue).
// One block per row, in-place fp16. grid (8192, 3)
__global__ __launch_bounds__(256) void ln_kernel(
    f16* __restrict__ P, const float* __restrict__ gamma,
    const float* __restrict__ beta)
{
  f16* p = P + (long)blockIdx.y * 8388608 + (long)blockIdx.x * 1024;
  const int tid = threadIdx.x;
  const int e = tid * 4;

  f16x4 raw = *(const f16x4*)(p + e);
  float v0 = (float)raw.x, v1 = (float)raw.y;
  float v2 = (float)raw.z, v3 = (float)raw.w;
  float s  = v0 + v1 + v2 + v3;
  float s2 = v0 * v0 + v1 * v1 + v2 * v2 + v3 * v3;

#pragma unroll
  for (int off = 32; off > 0; off >>= 1) {
    s  += __shfl_down(s, off, 64);
    s2 += __shfl_down(s2, off, 64);
  }
  __shared__ float red[10];
  const int wave = tid >> 6, lane = tid & 63;
  if (lane == 0) { red[wave] = s; red[4 + wave] = s2; }
  __syncthreads();
  if (tid == 0) {
    red[8] = red[0] + red[1] + red[2] + red[3];
    red[9] = red[4] + red[5] + red[6] + red[7];
  }
  __syncthreads();
  const float mu   = red[8] * (1.f / 1024.f);
  const float var  = red[9] * (1.f / 1024.f) - mu * mu;
  const float rstd = rsqrtf(var + 1e-5f);

  float4 gg = *(const float4*)(gamma + e);
  float4 be = *(const float4*)(beta + e);
  f16x4 o;
  o.x = (f16)((v0 - mu) * rstd * gg.x + be.x);
  o.y = (f16)((v1 - mu) * rstd * gg.y + be.y);
  o.z = (f16)((v2 - mu) * rstd * gg.z + be.z);
  o.w = (f16)((v3 - mu) * rstd * gg.w + be.w);
  *(f16x4*)(p + e) = o;
}

// V (S x D, fp16) -> Vt (D x S, fp16), per batch. grid (D/64, S/64, B)
__global__ __launch_bounds__(256) void transpose_kernel(const f16* __restrict__ V,
                                                        f16* __restrict__ Vt)
{
  const int S = 2048, D = 1024;
  const f16* v = V + (long)blockIdx.z * ((long)S * D);
  f16* vt = Vt + (long)blockIdx.z * ((long)D * S);
  __shared__ f16 tile[64][66];  // +2 pad -> conflict-free transposed reads
  const int d0 = blockIdx.x * 64, j0 = blockIdx.y * 64;
  const int tx = threadIdx.x & 63, ty = threadIdx.x >> 6;
#pragma unroll
  for (int r = ty; r < 64; r += 4)
    tile[r][tx] = v[(long)(j0 + r) * D + d0 + tx];
  __syncthreads();
#pragma unroll
  for (int r = ty; r < 64; r += 4)
    vt[(long)(d0 + r) * S + j0 + tx] = tile[tx][r];
}

// Row softmax over 2048 fp32 logits; writes fp16 probs in-place (first half of row).
__global__ __launch_bounds__(256) void softmax_kernel(float* __restrict__ Sc)
{
  float* srow = Sc + (long)blockIdx.x * 2048;
  const int tid = threadIdx.x;
  float4 a = ((const float4*)srow)[tid];
  float4 b = ((const float4*)srow)[256 + tid];

  float m = fmaxf(fmaxf(fmaxf(a.x, a.y), fmaxf(a.z, a.w)),
                  fmaxf(fmaxf(b.x, b.y), fmaxf(b.z, b.w)));
#pragma unroll
  for (int off = 32; off > 0; off >>= 1) m = fmaxf(m, __shfl_down(m, off, 64));
  __shared__ float red[6];
  const int wave = tid >> 6, lane = tid & 63;
  if (lane == 0) red[wave] = m;
  __syncthreads();
  if (tid == 0) red[4] = fmaxf(fmaxf(red[0], red[1]), fmaxf(red[2], red[3]));
  __syncthreads();
  const float M = red[4];

  a.x = __expf(a.x - M); a.y = __expf(a.y - M);
  a.z = __expf(a.z - M); a.w = __expf(a.w - M);
  b.x = __expf(b.x - M); b.y = __expf(b.y - M);
  b.z = __expf(b.z - M); b.w = __expf(b.w - M);
  float s = a.x + a.y + a.z + a.w + b.x + b.y + b.z + b.w;
#pragma unroll
  for (int off = 32; off > 0; off >>= 1) s += __shfl_down(s, off, 64);
  if (lane == 0) red[wave] = s;
  __syncthreads();
  if (tid == 0) red[5] = red[0] + red[1] + red[2] + red[3];
  __syncthreads();
  const float inv = 1.0f / red[5];

  f16* orow = (f16*)srow;  // safe: all reads happened before first barrier
  f16x4 oa, ob;
  oa.x = (f16)(a.x * inv); oa.y = (f16)(a.y * inv);
  oa.z = (f16)(a.z * inv); oa.w = (f16)(a.w * inv);
  ob.x = (f16)(b.x * inv); ob.y = (f16)(b.y * inv);
  ob.z = (f16)(b.z * inv); ob.w = (f16)(b.w * inv);
  ((f16x4*)orow)[tid]       = oa;
  ((f16x4*)orow)[256 + tid] = ob;
}

// ---------------------------------------------------------------------------
extern "C" void kernel_launch(void* const* d_in, const int* in_sizes, int n_in,
                              void* d_out, int out_size, void* d_ws, size_t ws_size,
                              hipStream_t stream)
{
  const float* x     = (const float*)d_in[0];
  const float* Wq    = (const float*)d_in[1];
  const float* bq    = (const float*)d_in[2];
  const float* Wk    = (const float*)d_in[3];
  const float* bk    = (const float*)d_in[4];
  const float* Wv    = (const float*)d_in[5];
  const float* bv    = (const float*)d_in[6];
  const float* gamma = (const float*)d_in[7];
  const float* beta  = (const float*)d_in[8];
  float* out = (float*)d_out;

  // ws layout (needs 128 MB):
  //  [0,48)MB   P  : Q,K,V fp16 slabs (8192x1024 each), LN in-place
  //  [48,64)MB  Vt : V transposed per batch (1024x2048 fp16)
  //  [64,128)MB Sc : scores fp32 (4 x 2048x2048); softmax writes fp16 probs in-place
  //  Xh/Wh aliased inside the Sc region (dead before scores are written)
  char* ws = (char*)d_ws;
  f16*   P  = (f16*)(ws);
  f16*   Vt = (f16*)(ws + (48u << 20));
  float* Sc = (float*)(ws + (64u << 20));
  f16*   Xh = (f16*)(ws + (64u << 20));
  f16*   Wh = (f16*)(ws + (80u << 20));

  // 1. fp32 -> fp16 casts (single launch)
  cast_all<<<11264, 256, 0, stream>>>(x, Wq, Wk, Wv, Xh, Wh);

  // 2. projections + bias: P_h = Xh · Wh^T + b_h  (M=8192, N=1024, K=1024, z=h)
  //    BM=128, BN=256 -> 64 x 4 x 3 = 768 blocks (3/CU, full pack)
  gemm8p<128, 256, f16, 0, true><<<768, 512, 0, stream>>>(
      Xh, Wh, P, 1024, 1024, 1024, 1024, 0L, 1048576L, 8388608L,
      4, 64, bq, bk, bv);

  // 3. LayerNorm (gamma/beta), in-place fp16
  ln_kernel<<<dim3(8192, 3), 256, 0, stream>>>(P, gamma, beta);

  // 4. V -> Vt per batch
  transpose_kernel<<<dim3(16, 32, 4), 256, 0, stream>>>(P + 2L * 8388608, Vt);

  // 5. scores: Sc_b = Q_b · K_b^T  (M=N=2048, K=1024, z=batch, fp32 out)
  //    BM=BN=256 -> 8 x 8 x 4 = 256 blocks (1/CU exact)
  gemm8p<256, 256, float, 1, false><<<256, 512, 0, stream>>>(
      P, P + 8388608, Sc, 1024, 1024, 2048, 1024, 2097152L, 2097152L, 4194304L,
      8, 8, nullptr, nullptr, nullptr);

  // 6. softmax rows (8192 rows), fp16 probs in-place (row pitch 4096 halves)
  softmax_kernel<<<8192, 256, 0, stream>>>(Sc);

  // 7. out_b = Pr_b · Vt_b^T  (M=2048, N=1024, K=2048, z=batch, fp32 out)
  //    BM=128, BN=256 -> 16 x 4 x 4 = 256 blocks (1/CU exact)
  gemm8p<128, 256, float, 1, false><<<256, 512, 0, stream>>>(
      (const f16*)Sc, Vt, out, 4096, 2048, 1024, 2048, 8388608L, 2097152L, 2097152L,
      4, 16, nullptr, nullptr, nullptr);
}

// Round 3
// 300.185 us; speedup vs baseline: 1.0512x; 1.0162x over previous
//
#include <hip/hip_runtime.h>

typedef _Float16 f16;
typedef __attribute__((ext_vector_type(4))) _Float16 f16x4;
typedef __attribute__((ext_vector_type(8))) _Float16 f16x8;
typedef __attribute__((ext_vector_type(4))) float f32x4;

#define GLB_AS __attribute__((address_space(1)))
#define LDS_AS __attribute__((address_space(3)))

__device__ __forceinline__ void async_copy16(const void* g, void* l) {
  // 16B-per-lane global->LDS DMA; LDS dest = wave-uniform base + lane*16
  __builtin_amdgcn_global_load_lds((const GLB_AS void*)g, (LDS_AS void*)l, 16, 0, 0);
}

#define WAITVM(N) asm volatile("s_waitcnt vmcnt(" #N ")" ::: "memory")
#define WAITLGKM0() asm volatile("s_waitcnt lgkmcnt(0)" ::: "memory")
#define BAR() __builtin_amdgcn_s_barrier()
#define SB0() __builtin_amdgcn_sched_barrier(0)

// Stage one K-half (32 of K) of tile t_ for A (IA insts) / B (IB=2 insts).
// Source global chunk is pre-inverse-swizzled (rule 21): LDS stays linear,
// reads apply the same XOR. Each inst covers 128 rows (8 waves x 16).
#define STAGE_A(t_, kk_) do {                                                \
    const long _k = (long)(t_) * 64 + (kk_) * 32;                            \
    f16* _d = &Ash[(t_) & 1][kk_][w16 * 32];                                 \
    async_copy16(Ag + _k, _d);                                               \
    if constexpr (IA == 2) async_copy16(Ag + _k + 128l * lda, _d + 4096);    \
  } while (0)
#define STAGE_B(t_, kk_) do {                                                \
    const long _k = (long)(t_) * 64 + (kk_) * 32;                            \
    f16* _d = &Bsh[(t_) & 1][kk_][w16 * 32];                                 \
    async_copy16(Bg + _k, _d);                                               \
    async_copy16(Bg + _k + 128l * ldb, _d + 4096);                           \
  } while (0)

// ---------------------------------------------------------------------------
// m201-style phase-split GEMM (T2+T3+T4+T5): C[m][n] = sum_k A[m][k]*B[n][k]
// 512 threads = 8 waves (2M x 4N). BK=64, staged as two K-halves (kk=0,1)
// per tile into Ash/Bsh[parity][kk]. 16-MFMA clusters per phase; 2 phases
// per K-tile (RM=4) or 4 (RM=8). Counted vmcnt: 3 half-tile groups (6 loads)
// stay in flight across every barrier; never vmcnt(0) until the tail.
//
// Steady-state stage schedule (RM=4): during tile t, phase1 stages
// {Ak1,Bk1}(t+1), phase2 stages {Ak0,Bk0}(t+2). Waits: end-p1 vmcnt(6)
// guarantees {Ak1,Bk1}(t) landed for p2; end-p2 vmcnt(6) guarantees
// {Ak0,Bk0}(t+1) for the next tile. WAR on LDS slots is fenced by the
// phase barriers (slot of Ak0(t+2) is dead after p1 of t; etc).
// RM=8 splits the same schedule across 4 phases (stage one unit/phase).
// Tail waits tighten 6 -> 4/3 -> 0 as staging runs out.
//
// LDS swizzle: chunk c of row r holds global chunk c ^ ((r ^ (r>>2)) & 3)
// -> 2-way banking on ds_read_b128 (free, m136); staging realizes it by
// pre-swizzling the per-lane global source (lane-only expression).
//
// MODE 0 (projection): y-inner, (x,z)-outer -> XCD j owns row-slab y==j mod 8
// MODE 1 (attention):  z = (n%8)>>1 -> batch bound to an XCD pair
// ---------------------------------------------------------------------------
template <int BM, int BN, typename OutT, int MODE, bool BIAS>
__global__ __launch_bounds__(512, 2) void gemm8p(
    const f16* __restrict__ A, const f16* __restrict__ B, OutT* __restrict__ C,
    int lda, int ldb, int ldc, int K, long sA, long sB, long sC,
    int tiles_x, int tiles_y,
    const float* __restrict__ b0, const float* __restrict__ b1,
    const float* __restrict__ b2)
{
  constexpr int WM = BM / 2, WN = BN / 4;     // per-wave output
  constexpr int RM = WM / 16, RN = WN / 16;   // frag repeats: (8,4) or (4,4)
  constexpr int IA = BM / 128;                // A insts per K-half
  static_assert(RN == 4 && BN == 256, "template assumes BN=256");

  __shared__ __align__(16) f16 Ash[2][2][BM * 32];
  __shared__ __align__(16) f16 Bsh[2][2][BN * 32];

  int bx, by, bz;
  {
    const int n = blockIdx.x;
    if (MODE == 0) {
      by = n % tiles_y;
      const int r = n / tiles_y;
      bx = r % tiles_x;
      bz = r / tiles_x;
    } else {
      const int j = n & 7, i = n >> 3, th = tiles_y >> 1;
      bz = j >> 1;
      bx = i / th;
      by = (j & 1) * th + i % th;
    }
  }

  A += (long)bz * sA;
  B += (long)bz * sB;
  C += (long)bz * sC;

  const int tid  = threadIdx.x;
  const int wave = tid >> 6, lane = tid & 63;
  const int wr = wave >> 2, wc = wave & 3;
  const int m0 = by * BM, n0 = bx * BN;
  const int r16 = lane & 15, quad = lane >> 4;
  const int w16 = wave * 16;

  // staging source: row = [inst*128 +] w16 + (lane>>2); chunk pre-swizzled
  const int cg8 = (((lane & 3) ^ ((lane >> 2) & 3) ^ ((lane >> 4) & 3)) * 8);
  const f16* Ag = A + (long)(m0 + w16 + (lane >> 2)) * lda + cg8;
  const f16* Bg = B + (long)(n0 + w16 + (lane >> 2)) * ldb + cg8;

  const int NT = K / 64;  // >= 16 for all shapes here

  // prologue: {Ak0,Bk0}(0), {Ak1,Bk1}(0), {Ak0,Bk0}(1)
  STAGE_A(0, 0); STAGE_B(0, 0);
  STAGE_A(0, 1); STAGE_B(0, 1);
  STAGE_A(1, 0); STAGE_B(1, 0);

  f32x4 acc[RM][RN] = {};

  // fragment reads: row = w-base + frag*16 + r16, chunk = quad ^ swz(r16)
  const int rc  = (quad ^ ((r16 ^ (r16 >> 2)) & 3)) * 8;
  const int rdA = (wr * WM + r16) * 32 + rc;
  const int rdB = (wc * WN + r16) * 32 + rc;

  if constexpr (RM == 8) { WAITVM(8); } else { WAITVM(6); }
  BAR();

  for (int t = 0; t < NT; ++t) {
    const int bp = t & 1;
    const f16* A0 = &Ash[bp][0][0];
    const f16* A1 = &Ash[bp][1][0];
    const f16* B0 = &Bsh[bp][0][0];
    const f16* B1 = &Bsh[bp][1][0];
    f16x8 af[4], bf[4];

    if constexpr (RM == 4) {
      // ---- phase 1: kk=0
#pragma unroll
      for (int i = 0; i < 4; i++) af[i] = *(const f16x8*)&A0[rdA + i * 512];
#pragma unroll
      for (int j = 0; j < 4; j++) bf[j] = *(const f16x8*)&B0[rdB + j * 512];
      if (t + 1 < NT) { STAGE_A(t + 1, 1); STAGE_B(t + 1, 1); }
      BAR();
      WAITLGKM0(); SB0();
      __builtin_amdgcn_s_setprio(1);
#pragma unroll
      for (int i = 0; i < 4; i++)
#pragma unroll
        for (int j = 0; j < 4; j++)
          acc[i][j] = __builtin_amdgcn_mfma_f32_16x16x32_f16(af[i], bf[j], acc[i][j], 0, 0, 0);
      __builtin_amdgcn_s_setprio(0); SB0();
      if (t < NT - 1) { WAITVM(6); } else { WAITVM(0); }
      BAR();
      // ---- phase 2: kk=1
#pragma unroll
      for (int i = 0; i < 4; i++) af[i] = *(const f16x8*)&A1[rdA + i * 512];
#pragma unroll
      for (int j = 0; j < 4; j++) bf[j] = *(const f16x8*)&B1[rdB + j * 512];
      if (t + 2 < NT) { STAGE_A(t + 2, 0); STAGE_B(t + 2, 0); }
      BAR();
      WAITLGKM0(); SB0();
      __builtin_amdgcn_s_setprio(1);
#pragma unroll
      for (int i = 0; i < 4; i++)
#pragma unroll
        for (int j = 0; j < 4; j++)
          acc[i][j] = __builtin_amdgcn_mfma_f32_16x16x32_f16(af[i], bf[j], acc[i][j], 0, 0, 0);
      __builtin_amdgcn_s_setprio(0); SB0();
      if (t < NT - 2) { WAITVM(6); } else if (t == NT - 2) { WAITVM(3); } else { WAITVM(0); }
      BAR();
    } else {
      // ---- phase 1: kk=0, rows 0-3
#pragma unroll
      for (int i = 0; i < 4; i++) af[i] = *(const f16x8*)&A0[rdA + i * 512];
#pragma unroll
      for (int j = 0; j < 4; j++) bf[j] = *(const f16x8*)&B0[rdB + j * 512];
      if (t + 1 < NT) STAGE_A(t + 1, 1);
      BAR();
      WAITLGKM0(); SB0();
      __builtin_amdgcn_s_setprio(1);
#pragma unroll
      for (int i = 0; i < 4; i++)
#pragma unroll
        for (int j = 0; j < 4; j++)
          acc[i][j] = __builtin_amdgcn_mfma_f32_16x16x32_f16(af[i], bf[j], acc[i][j], 0, 0, 0);
      __builtin_amdgcn_s_setprio(0); SB0();
      BAR();
      // ---- phase 2: kk=0, rows 4-7
#pragma unroll
      for (int i = 0; i < 4; i++) af[i] = *(const f16x8*)&A0[rdA + (4 + i) * 512];
      if (t + 1 < NT) STAGE_B(t + 1, 1);
      BAR();
      WAITLGKM0(); SB0();
      __builtin_amdgcn_s_setprio(1);
#pragma unroll
      for (int i = 0; i < 4; i++)
#pragma unroll
        for (int j = 0; j < 4; j++)
          acc[4 + i][j] = __builtin_amdgcn_mfma_f32_16x16x32_f16(af[i], bf[j], acc[4 + i][j], 0, 0, 0);
      __builtin_amdgcn_s_setprio(0); SB0();
      if (t < NT - 1) { WAITVM(6); } else { WAITVM(0); }
      BAR();
      // ---- phase 3: kk=1, rows 0-3
#pragma unroll
      for (int i = 0; i < 4; i++) af[i] = *(const f16x8*)&A1[rdA + i * 512];
#pragma unroll
      for (int j = 0; j < 4; j++) bf[j] = *(const f16x8*)&B1[rdB + j * 512];
      if (t + 2 < NT) STAGE_A(t + 2, 0);
      BAR();
      WAITLGKM0(); SB0();
      __builtin_amdgcn_s_setprio(1);
#pragma unroll
      for (int i = 0; i < 4; i++)
#pragma unroll
        for (int j = 0; j < 4; j++)
          acc[i][j] = __builtin_amdgcn_mfma_f32_16x16x32_f16(af[i], bf[j], acc[i][j], 0, 0, 0);
      __builtin_amdgcn_s_setprio(0); SB0();
      BAR();
      // ---- phase 4: kk=1, rows 4-7
#pragma unroll
      for (int i = 0; i < 4; i++) af[i] = *(const f16x8*)&A1[rdA + (4 + i) * 512];
      if (t + 2 < NT) STAGE_B(t + 2, 0);
      BAR();
      WAITLGKM0(); SB0();
      __builtin_amdgcn_s_setprio(1);
#pragma unroll
      for (int i = 0; i < 4; i++)
#pragma unroll
        for (int j = 0; j < 4; j++)
          acc[4 + i][j] = __builtin_amdgcn_mfma_f32_16x16x32_f16(af[i], bf[j], acc[4 + i][j], 0, 0, 0);
      __builtin_amdgcn_s_setprio(0); SB0();
      if (t < NT - 2) { WAITVM(6); } else if (t == NT - 2) { WAITVM(4); } else { WAITVM(0); }
      BAR();
    }
  }

  // epilogue. C/D layout (verified m89): col = lane&15, row = (lane>>4)*4 + reg
  float bias_j[RN];
#pragma unroll
  for (int j = 0; j < RN; j++) bias_j[j] = 0.f;
  if constexpr (BIAS) {
    const float* bias = (bz == 0) ? b0 : (bz == 1) ? b1 : b2;
#pragma unroll
    for (int j = 0; j < RN; j++) bias_j[j] = bias[n0 + wc * WN + j * 16 + r16];
  }
#pragma unroll
  for (int i = 0; i < RM; i++)
#pragma unroll
    for (int j = 0; j < RN; j++)
#pragma unroll
      for (int r = 0; r < 4; r++) {
        long row = m0 + wr * WM + i * 16 + quad * 4 + r;
        long col = n0 + wc * WN + j * 16 + r16;
        C[row * (long)ldc + col] = (OutT)(acc[i][j][r] + bias_j[j]);
      }
}

// ---------------------------------------------------------------------------
// One launch casts x (8.39M) + Wq/Wk/Wv (1.05M each) fp32 -> fp16.
__global__ __launch_bounds__(256) void cast_all(
    const float* __restrict__ x, const float* __restrict__ Wq,
    const float* __restrict__ Wk, const float* __restrict__ Wv,
    f16* __restrict__ Xh, f16* __restrict__ Wh)
{
  const long off = (long)blockIdx.x * 1024 + threadIdx.x * 4;
  const float* src;
  f16* dst;
  if (off < 8388608L) {
    src = x + off;
    dst = Xh + off;
  } else {
    const long o = off - 8388608L;
    src = (o < 1048576L) ? Wq + o
        : (o < 2097152L) ? Wk + (o - 1048576L)
                         : Wv + (o - 2097152L);
    dst = Wh + o;
  }
  const float4 v = *(const float4*)src;
  f16x4 h;
  h.x = (f16)v.x; h.y = (f16)v.y; h.z = (f16)v.z; h.w = (f16)v.w;
  *(f16x4*)dst = h;
}

// LayerNorm (gamma/beta; bias already folded into GEMM epilogue).
// One block per row, in-place fp16. grid (8192, 3)
__global__ __launch_bounds__(256) void ln_kernel(
    f16* __restrict__ P, const float* __restrict__ gamma,
    const float* __restrict__ beta)
{
  f16* p = P + (long)blockIdx.y * 8388608 + (long)blockIdx.x * 1024;
  const int tid = threadIdx.x;
  const int e = tid * 4;

  f16x4 raw = *(const f16x4*)(p + e);
  float v0 = (float)raw.x, v1 = (float)raw.y;
  float v2 = (float)raw.z, v3 = (float)raw.w;
  float s  = v0 + v1 + v2 + v3;
  float s2 = v0 * v0 + v1 * v1 + v2 * v2 + v3 * v3;

#pragma unroll
  for (int off = 32; off > 0; off >>= 1) {
    s  += __shfl_down(s, off, 64);
    s2 += __shfl_down(s2, off, 64);
  }
  __shared__ float red[10];
  const int wave = tid >> 6, lane = tid & 63;
  if (lane == 0) { red[wave] = s; red[4 + wave] = s2; }
  __syncthreads();
  if (tid == 0) {
    red[8] = red[0] + red[1] + red[2] + red[3];
    red[9] = red[4] + red[5] + red[6] + red[7];
  }
  __syncthreads();
  const float mu   = red[8] * (1.f / 1024.f);
  const float var  = red[9] * (1.f / 1024.f) - mu * mu;
  const float rstd = rsqrtf(var + 1e-5f);

  float4 gg = *(const float4*)(gamma + e);
  float4 be = *(const float4*)(beta + e);
  f16x4 o;
  o.x = (f16)((v0 - mu) * rstd * gg.x + be.x);
  o.y = (f16)((v1 - mu) * rstd * gg.y + be.y);
  o.z = (f16)((v2 - mu) * rstd * gg.z + be.z);
  o.w = (f16)((v3 - mu) * rstd * gg.w + be.w);
  *(f16x4*)(p + e) = o;
}

// V (S x D, fp16) -> Vt (D x S, fp16), per batch. grid (D/64, S/64, B)
__global__ __launch_bounds__(256) void transpose_kernel(const f16* __restrict__ V,
                                                        f16* __restrict__ Vt)
{
  const int S = 2048, D = 1024;
  const f16* v = V + (long)blockIdx.z * ((long)S * D);
  f16* vt = Vt + (long)blockIdx.z * ((long)D * S);
  __shared__ f16 tile[64][66];  // +2 pad -> conflict-free transposed reads
  const int d0 = blockIdx.x * 64, j0 = blockIdx.y * 64;
  const int tx = threadIdx.x & 63, ty = threadIdx.x >> 6;
#pragma unroll
  for (int r = ty; r < 64; r += 4)
    tile[r][tx] = v[(long)(j0 + r) * D + d0 + tx];
  __syncthreads();
#pragma unroll
  for (int r = ty; r < 64; r += 4)
    vt[(long)(d0 + r) * S + j0 + tx] = tile[tx][r];
}

// Row softmax over 2048 fp32 logits; writes fp16 probs in-place (first half of row).
__global__ __launch_bounds__(256) void softmax_kernel(float* __restrict__ Sc)
{
  float* srow = Sc + (long)blockIdx.x * 2048;
  const int tid = threadIdx.x;
  float4 a = ((const float4*)srow)[tid];
  float4 b = ((const float4*)srow)[256 + tid];

  float m = fmaxf(fmaxf(fmaxf(a.x, a.y), fmaxf(a.z, a.w)),
                  fmaxf(fmaxf(b.x, b.y), fmaxf(b.z, b.w)));
#pragma unroll
  for (int off = 32; off > 0; off >>= 1) m = fmaxf(m, __shfl_down(m, off, 64));
  __shared__ float red[6];
  const int wave = tid >> 6, lane = tid & 63;
  if (lane == 0) red[wave] = m;
  __syncthreads();
  if (tid == 0) red[4] = fmaxf(fmaxf(red[0], red[1]), fmaxf(red[2], red[3]));
  __syncthreads();
  const float M = red[4];

  a.x = __expf(a.x - M); a.y = __expf(a.y - M);
  a.z = __expf(a.z - M); a.w = __expf(a.w - M);
  b.x = __expf(b.x - M); b.y = __expf(b.y - M);
  b.z = __expf(b.z - M); b.w = __expf(b.w - M);
  float s = a.x + a.y + a.z + a.w + b.x + b.y + b.z + b.w;
#pragma unroll
  for (int off = 32; off > 0; off >>= 1) s += __shfl_down(s, off, 64);
  if (lane == 0) red[wave] = s;
  __syncthreads();
  if (tid == 0) red[5] = red[0] + red[1] + red[2] + red[3];
  __syncthreads();
  const float inv = 1.0f / red[5];

  f16* orow = (f16*)srow;  // safe: all reads happened before first barrier
  f16x4 oa, ob;
  oa.x = (f16)(a.x * inv); oa.y = (f16)(a.y * inv);
  oa.z = (f16)(a.z * inv); oa.w = (f16)(a.w * inv);
  ob.x = (f16)(b.x * inv); ob.y = (f16)(b.y * inv);
  ob.z = (f16)(b.z * inv); ob.w = (f16)(b.w * inv);
  ((f16x4*)orow)[tid]       = oa;
  ((f16x4*)orow)[256 + tid] = ob;
}

// ---------------------------------------------------------------------------
extern "C" void kernel_launch(void* const* d_in, const int* in_sizes, int n_in,
                              void* d_out, int out_size, void* d_ws, size_t ws_size,
                              hipStream_t stream)
{
  const float* x     = (const float*)d_in[0];
  const float* Wq    = (const float*)d_in[1];
  const float* bq    = (const float*)d_in[2];
  const float* Wk    = (const float*)d_in[3];
  const float* bk    = (const float*)d_in[4];
  const float* Wv    = (const float*)d_in[5];
  const float* bv    = (const float*)d_in[6];
  const float* gamma = (const float*)d_in[7];
  const float* beta  = (const float*)d_in[8];
  float* out = (float*)d_out;

  // ws layout (needs 128 MB):
  //  [0,48)MB   P  : Q,K,V fp16 slabs (8192x1024 each), LN in-place
  //  [48,64)MB  Vt : V transposed per batch (1024x2048 fp16)
  //  [64,128)MB Sc : scores fp32 (4 x 2048x2048); softmax writes fp16 probs in-place
  //  Xh/Wh aliased inside the Sc region (dead before scores are written)
  char* ws = (char*)d_ws;
  f16*   P  = (f16*)(ws);
  f16*   Vt = (f16*)(ws + (48u << 20));
  float* Sc = (float*)(ws + (64u << 20));
  f16*   Xh = (f16*)(ws + (64u << 20));
  f16*   Wh = (f16*)(ws + (80u << 20));

  // 1. fp32 -> fp16 casts (single launch)
  cast_all<<<11264, 256, 0, stream>>>(x, Wq, Wk, Wv, Xh, Wh);

  // 2. projections + bias: P_h = Xh · Wh^T + b_h  (M=8192, N=1024, K=1024, z=h)
  //    BM=128, BN=256 -> 64 x 4 x 3 = 768 blocks (3/CU exact)
  gemm8p<128, 256, f16, 0, true><<<768, 512, 0, stream>>>(
      Xh, Wh, P, 1024, 1024, 1024, 1024, 0L, 1048576L, 8388608L,
      4, 64, bq, bk, bv);

  // 3. LayerNorm (gamma/beta), in-place fp16
  ln_kernel<<<dim3(8192, 3), 256, 0, stream>>>(P, gamma, beta);

  // 4. V -> Vt per batch
  transpose_kernel<<<dim3(16, 32, 4), 256, 0, stream>>>(P + 2L * 8388608, Vt);

  // 5. scores: Sc_b = Q_b · K_b^T  (M=N=2048, K=1024, z=batch, fp32 out)
  //    BM=BN=256 -> 8 x 8 x 4 = 256 blocks (1/CU exact, full m201 geometry)
  gemm8p<256, 256, float, 1, false><<<256, 512, 0, stream>>>(
      P, P + 8388608, Sc, 1024, 1024, 2048, 1024, 2097152L, 2097152L, 4194304L,
      8, 8, nullptr, nullptr, nullptr);

  // 6. softmax rows (8192 rows), fp16 probs in-place (row pitch 4096 halves)
  softmax_kernel<<<8192, 256, 0, stream>>>(Sc);

  // 7. out_b = Pr_b · Vt_b^T  (M=2048, N=1024, K=2048, z=batch, fp32 out)
  //    BM=128, BN=256 -> 16 x 4 x 4 = 256 blocks (1/CU exact)
  gemm8p<128, 256, float, 1, false><<<256, 512, 0, stream>>>(
      (const f16*)Sc, Vt, out, 4096, 2048, 1024, 2048, 8388608L, 2097152L, 2097152L,
      4, 16, nullptr, nullptr, nullptr);
}